// Round 1
// baseline (17507.857 us; speedup 1.0000x reference)
//
#include <hip/hip_runtime.h>
#include <hip/hip_cooperative_groups.h>

namespace cg = cooperative_groups;

typedef __bf16 bf16;
typedef __bf16 bf16x8 __attribute__((ext_vector_type(8)));
typedef float f32x4 __attribute__((ext_vector_type(4)));

// Problem dims
#define TT 256
#define BB 64
#define EE 1024
#define HH 1024
#define NTAGS 50
#define NROW 16384  // T*B

// Workspace layout (bytes)
#define OFF_EMB   0ull                        // bf16 [16384][1024] gathered embedding
#define OFF_WIH   (OFF_EMB  + 33554432ull)    // bf16 [1024][1024]
#define OFF_WHH   (OFF_WIH  + 2097152ull)
#define OFF_WCH   (OFF_WHH  + 2097152ull)
#define OFF_WC2H  (OFF_WCH  + 2097152ull)
#define OFF_DW    (OFF_WC2H + 2097152ull)     // bf16 [64][1024] (tags padded to 64)
#define OFF_XW    (OFF_DW   + 131072ull)      // bf16 [16384][1024]  x@Wih^T + b_ih + b_hh
#define OFF_HIST  (OFF_XW   + 33554432ull)    // bf16 [257][64][1024] h history (slot0 = h0)
#define OFF_CB    (OFF_HIST + 33685504ull)    // bf16 [2][64][1024]  c state (bf16 copy)
#define OFF_CF    (OFF_CB   + 262144ull)      // f32  [2][64][1024]  c state (f32)

// ---------------- prep: convert weights to bf16, gather embedding rows ----------------
__global__ void k_prep(const int* __restrict__ X, const float* __restrict__ emb,
                       const float* __restrict__ wih, const float* __restrict__ whh,
                       const float* __restrict__ wch, const float* __restrict__ wc2h,
                       const float* __restrict__ dw, const float* __restrict__ h0,
                       const float* __restrict__ c0, char* __restrict__ ws) {
  const long N_W = 4194304, N_DW = 65536, N_EMB = 16777216, N_H = 65536, N_C = 65536;
  const long TOT = N_W + N_DW + N_EMB + N_H + N_C;
  long stride = (long)gridDim.x * blockDim.x;
  for (long idx = (long)blockIdx.x * blockDim.x + threadIdx.x; idx < TOT; idx += stride) {
    if (idx < N_W) {
      long m = idx >> 20, e = idx & 1048575;
      const float* s = (m == 0) ? wih : (m == 1) ? whh : (m == 2) ? wch : wc2h;
      ((bf16*)(ws + OFF_WIH))[idx] = (bf16)s[e];   // 4 matrices contiguous in ws
    } else if (idx < N_W + N_DW) {
      long j = idx - N_W; long r = j >> 10, e = j & 1023;
      ((bf16*)(ws + OFF_DW))[j] = (bf16)((r < NTAGS) ? dw[r * 1024 + e] : 0.f);
    } else if (idx < N_W + N_DW + N_EMB) {
      long j = idx - N_W - N_DW; long i = j >> 10, e = j & 1023;
      ((bf16*)(ws + OFF_EMB))[j] = (bf16)emb[(long)X[i] * 1024 + e];
    } else if (idx < N_W + N_DW + N_EMB + N_H) {
      long j = idx - N_W - N_DW - N_EMB;
      ((bf16*)(ws + OFF_HIST))[j] = (bf16)h0[j];
    } else {
      long j = idx - N_W - N_DW - N_EMB - N_H;
      ((float*)(ws + OFF_CF))[j] = c0[j];
      ((bf16*)(ws + OFF_CB))[j] = (bf16)c0[j];
    }
  }
}

// ---------------- XW = emb @ Wih^T + b_ih + b_hh  (bf16 MFMA) ----------------
// grid (256,16), block 256. Each wave: 16 rows x 64 cols, K=1024.
__global__ __launch_bounds__(256) void k_xw(const float* __restrict__ b_ih,
                                            const float* __restrict__ b_hh,
                                            char* __restrict__ ws) {
  const bf16* emb = (const bf16*)(ws + OFF_EMB);
  const bf16* wih = (const bf16*)(ws + OFF_WIH);
  bf16* xw = (bf16*)(ws + OFF_XW);
  int l = threadIdx.x & 63, wv = threadIdx.x >> 6;
  int i0 = blockIdx.x * 64 + wv * 16;
  int h0 = blockIdx.y * 64;
  const bf16* ap = emb + (long)(i0 + (l & 15)) * 1024 + ((l >> 4) * 8);
  const bf16* bp = wih + (long)(h0 + (l & 15)) * 1024 + ((l >> 4) * 8);
  f32x4 zero = {0.f, 0.f, 0.f, 0.f};
  f32x4 acc[4] = {zero, zero, zero, zero};
  for (int k = 0; k < 1024; k += 32) {
    bf16x8 a = *(const bf16x8*)(ap + k);
#pragma unroll
    for (int j = 0; j < 4; ++j) {
      bf16x8 b = *(const bf16x8*)(bp + j * 16 * 1024 + k);
      acc[j] = __builtin_amdgcn_mfma_f32_16x16x32_bf16(a, b, acc[j], 0, 0, 0);
    }
  }
#pragma unroll
  for (int j = 0; j < 4; ++j)
#pragma unroll
    for (int r = 0; r < 4; ++r) {
      int row = i0 + (l >> 4) * 4 + r;
      int col = h0 + j * 16 + (l & 15);
      xw[(long)row * 1024 + col] = (bf16)(acc[j][r] + b_ih[col] + b_hh[col]);
    }
}

// ---------------- recurrence: cooperative, 256 blocks x 256 thr ----------------
// Block = one 16x16 output tile (b0,h0). 4 waves K-split (256 each), LDS reduce.
// Per-thread element (gb,gh) carries pre/cy in registers across grid.sync.
__global__ __launch_bounds__(256) void k_rnn(const float* __restrict__ b_ch,
                                             const float* __restrict__ b_c2h,
                                             char* __restrict__ ws) {
  const bf16* xw   = (const bf16*)(ws + OFF_XW);
  const bf16* whh  = (const bf16*)(ws + OFF_WHH);
  const bf16* wch  = (const bf16*)(ws + OFF_WCH);
  const bf16* wc2h = (const bf16*)(ws + OFF_WC2H);
  bf16* hist = (bf16*)(ws + OFF_HIST);
  bf16* cb   = (bf16*)(ws + OFF_CB);
  float* cf  = (float*)(ws + OFF_CF);

  cg::grid_group grid = cg::this_grid();

  int l = threadIdx.x & 63, wv = threadIdx.x >> 6;
  int tile = blockIdx.x;
  int b0 = (tile >> 6) * 16;
  int h0 = (tile & 63) * 16;
  int e = threadIdx.x;
  int eoff = (b0 + (e >> 4)) * 1024 + h0 + (e & 15);  // this thread's (b,h) flat offset
  int gh = h0 + (e & 15);

  __shared__ float red[4][2][256];

  int kbase = wv * 256;
  int lane_r = l & 15, lane_k = (l >> 4) * 8;
  const bf16* whh_p  = whh  + (long)(h0 + lane_r) * 1024 + lane_k + kbase;
  const bf16* wch_p  = wch  + (long)(h0 + lane_r) * 1024 + lane_k + kbase;
  const bf16* wc2h_p = wc2h + (long)(h0 + lane_r) * 1024 + lane_k + kbase;
  long arow_off = (long)(b0 + lane_r) * 1024 + lane_k + kbase;

  float bch_v = b_ch[gh], bc2h_v = b_c2h[gh];
  f32x4 zero = {0.f, 0.f, 0.f, 0.f};

  for (int t = 0; t < TT; ++t) {
    const bf16* hx  = hist + (long)t * 65536;
    const bf16* cxb = cb + (long)(t & 1) * 65536;
    bf16* cyb = cb + (long)((t + 1) & 1) * 65536;
    const float* cxf = cf + (long)(t & 1) * 65536;
    float* cyf = cf + (long)((t + 1) & 1) * 65536;

    // ---- phase A: pre-tile (hx@Whh) and cg-tile (cx@Wch), K-split over waves
    f32x4 ap_ = zero, ac_ = zero;
#pragma unroll
    for (int kk = 0; kk < 256; kk += 32) {
      bf16x8 a1 = *(const bf16x8*)(hx + arow_off + kk);
      bf16x8 w1 = *(const bf16x8*)(whh_p + kk);
      ap_ = __builtin_amdgcn_mfma_f32_16x16x32_bf16(a1, w1, ap_, 0, 0, 0);
      bf16x8 a2 = *(const bf16x8*)(cxb + arow_off + kk);
      bf16x8 w2 = *(const bf16x8*)(wch_p + kk);
      ac_ = __builtin_amdgcn_mfma_f32_16x16x32_bf16(a2, w2, ac_, 0, 0, 0);
    }
#pragma unroll
    for (int r = 0; r < 4; ++r) {
      int ei = ((l >> 4) * 4 + r) * 16 + (l & 15);
      red[wv][0][ei] = ap_[r];
      red[wv][1][ei] = ac_[r];
    }
    __syncthreads();
    float pre = red[0][0][e] + red[1][0][e] + red[2][0][e] + red[3][0][e]
              + (float)xw[(long)t * 65536 + eoff];
    float cgm = red[0][1][e] + red[1][1][e] + red[2][1][e] + red[3][1][e] + bch_v;
    float cxv = cxf[eoff];
    float gif = 1.f / (1.f + expf(-(pre + cgm)));
    float cgt = tanhf(pre);
    float cy = gif * (cxv + cgt);
    cyf[eoff] = cy;
    cyb[eoff] = (bf16)cy;
    grid.sync();

    // ---- phase B: o-tile (cy@Wc2h)
    f32x4 ao = zero;
#pragma unroll
    for (int kk = 0; kk < 256; kk += 32) {
      bf16x8 a3 = *(const bf16x8*)(cyb + arow_off + kk);
      bf16x8 w3 = *(const bf16x8*)(wc2h_p + kk);
      ao = __builtin_amdgcn_mfma_f32_16x16x32_bf16(a3, w3, ao, 0, 0, 0);
    }
#pragma unroll
    for (int r = 0; r < 4; ++r)
      red[wv][0][((l >> 4) * 4 + r) * 16 + (l & 15)] = ao[r];
    __syncthreads();
    float o = red[0][0][e] + red[1][0][e] + red[2][0][e] + red[3][0][e] + bc2h_v;
    float og = 1.f / (1.f + expf(-(pre + o)));
    float hy = og * tanhf(cy);
    hist[(long)(t + 1) * 65536 + eoff] = (bf16)hy;
    grid.sync();
  }
}

// ---------------- dense + softmax ----------------
// grid 256, block 256. Wave: 16 rows x 64 tags (padded), then 16-lane-group softmax.
__global__ __launch_bounds__(256) void k_out(const float* __restrict__ dense_b,
                                             const char* __restrict__ ws,
                                             float* __restrict__ out) {
  const bf16* h  = (const bf16*)(ws + OFF_HIST) + 65536;  // slot1.. = hy(t)
  const bf16* dw = (const bf16*)(ws + OFF_DW);
  int l = threadIdx.x & 63, wv = threadIdx.x >> 6;
  int i0 = blockIdx.x * 64 + wv * 16;
  const bf16* ap = h  + (long)(i0 + (l & 15)) * 1024 + ((l >> 4) * 8);
  const bf16* bp = dw + (long)(l & 15) * 1024 + ((l >> 4) * 8);
  f32x4 zero = {0.f, 0.f, 0.f, 0.f};
  f32x4 acc[4] = {zero, zero, zero, zero};
  for (int k = 0; k < 1024; k += 32) {
    bf16x8 a = *(const bf16x8*)(ap + k);
#pragma unroll
    for (int j = 0; j < 4; ++j) {
      bf16x8 b = *(const bf16x8*)(bp + j * 16 * 1024 + k);
      acc[j] = __builtin_amdgcn_mfma_f32_16x16x32_bf16(a, b, acc[j], 0, 0, 0);
    }
  }
  int tag0 = l & 15;
#pragma unroll
  for (int r = 0; r < 4; ++r) {
    int row = i0 + (l >> 4) * 4 + r;
    float lg[4], ex[4];
    float mx = -1e30f;
#pragma unroll
    for (int j = 0; j < 4; ++j) {
      int tag = j * 16 + tag0;
      lg[j] = (tag < NTAGS) ? (acc[j][r] + dense_b[tag]) : -1e30f;
      mx = fmaxf(mx, lg[j]);
    }
    for (int m = 1; m < 16; m <<= 1) mx = fmaxf(mx, __shfl_xor(mx, m, 64));
    float s = 0.f;
#pragma unroll
    for (int j = 0; j < 4; ++j) {
      int tag = j * 16 + tag0;
      ex[j] = (tag < NTAGS) ? expf(lg[j] - mx) : 0.f;
      s += ex[j];
    }
    for (int m = 1; m < 16; m <<= 1) s += __shfl_xor(s, m, 64);
    float inv = 1.f / s;
#pragma unroll
    for (int j = 0; j < 4; ++j) {
      int tag = j * 16 + tag0;
      if (tag < NTAGS) out[(long)row * 50 + tag] = ex[j] * inv;
    }
  }
}

extern "C" void kernel_launch(void* const* d_in, const int* in_sizes, int n_in,
                              void* d_out, int out_size, void* d_ws, size_t ws_size,
                              hipStream_t stream) {
  const int*   X        = (const int*)d_in[0];
  // d_in[1] = lengths (unused; all == T)
  const float* embedding = (const float*)d_in[2];
  const float* w_ih  = (const float*)d_in[3];
  const float* w_hh  = (const float*)d_in[4];
  const float* w_ch  = (const float*)d_in[5];
  const float* w_c2h = (const float*)d_in[6];
  const float* b_ih  = (const float*)d_in[7];
  const float* b_hh  = (const float*)d_in[8];
  const float* b_ch  = (const float*)d_in[9];
  const float* b_c2h = (const float*)d_in[10];
  const float* dense_w = (const float*)d_in[11];
  const float* dense_b = (const float*)d_in[12];
  const float* h0 = (const float*)d_in[13];
  const float* c0 = (const float*)d_in[14];
  char* ws = (char*)d_ws;
  float* out = (float*)d_out;

  k_prep<<<4096, 256, 0, stream>>>(X, embedding, w_ih, w_hh, w_ch, w_c2h,
                                   dense_w, h0, c0, ws);
  k_xw<<<dim3(256, 16), 256, 0, stream>>>(b_ih, b_hh, ws);

  void* args[] = {(void*)&b_ch, (void*)&b_c2h, (void*)&ws};
  hipLaunchCooperativeKernel((const void*)k_rnn, dim3(256), dim3(256), args, 0, stream);

  k_out<<<256, 256, 0, stream>>>(dense_b, ws, out);
}

// Round 3
// 6209.922 us; speedup vs baseline: 2.8193x; 2.8193x over previous
//
#include <hip/hip_runtime.h>
#include <hip/hip_cooperative_groups.h>

typedef __bf16 bf16;
typedef __bf16 bf16x8 __attribute__((ext_vector_type(8)));
typedef float f32x4 __attribute__((ext_vector_type(4)));

// Problem dims
#define TT 256
#define NTAGS 50

// Workspace layout (bytes)
#define OFF_WIH   0ull                       // bf16 [1024][1024]
#define OFF_WHH   (OFF_WIH  + 2097152ull)
#define OFF_WCH   (OFF_WHH  + 2097152ull)
#define OFF_WC2H  (OFF_WCH  + 2097152ull)
#define OFF_DW    (OFF_WC2H + 2097152ull)    // bf16 [64][1024] (tags padded to 64)
#define OFF_XW    (OFF_DW   + 131072ull)     // bf16 [16384][1024]  x@Wih^T + b_ih + b_hh
#define OFF_HIST  (OFF_XW   + 33554432ull)   // bf16 [257][64][1024] h history (slot0 = h0)
#define OFF_CB    (OFF_HIST + 33685504ull)   // bf16 [2][64][1024]  c state (bf16 copy)
#define OFF_BAR   (OFF_CB   + 262144ull)     // uint [4][64] barrier flags (+pad)
// total ~72.5 MB

// ---------------- prep: weights->bf16, h0/c0 state init, barrier flags=0 ----------------
__global__ void k_prep(const float* __restrict__ wih, const float* __restrict__ whh,
                       const float* __restrict__ wch, const float* __restrict__ wc2h,
                       const float* __restrict__ dw, const float* __restrict__ h0,
                       const float* __restrict__ c0, char* __restrict__ ws) {
  const long N_W = 4194304, N_DW = 65536, N_H = 65536, N_C = 65536, N_F = 256;
  const long TOT = N_W + N_DW + N_H + N_C + N_F;
  long stride = (long)gridDim.x * blockDim.x;
  for (long idx = (long)blockIdx.x * blockDim.x + threadIdx.x; idx < TOT; idx += stride) {
    if (idx < N_W) {
      long m = idx >> 20, e = idx & 1048575;
      const float* s = (m == 0) ? wih : (m == 1) ? whh : (m == 2) ? wch : wc2h;
      ((bf16*)(ws + OFF_WIH))[idx] = (bf16)s[e];
    } else if (idx < N_W + N_DW) {
      long j = idx - N_W; long r = j >> 10, e = j & 1023;
      ((bf16*)(ws + OFF_DW))[j] = (bf16)((r < NTAGS) ? dw[r * 1024 + e] : 0.f);
    } else if (idx < N_W + N_DW + N_H) {
      long j = idx - N_W - N_DW;
      ((bf16*)(ws + OFF_HIST))[j] = (bf16)h0[j];
    } else if (idx < N_W + N_DW + N_H + N_C) {
      long j = idx - N_W - N_DW - N_H;
      ((bf16*)(ws + OFF_CB))[j] = (bf16)c0[j];
    } else {
      long j = idx - N_W - N_DW - N_H - N_C;
      ((unsigned int*)(ws + OFF_BAR))[j] = 0u;   // re-init every launch (replay safety)
    }
  }
}

// ---------------- XW = emb[X] @ Wih^T + b_ih + b_hh  (gather fused) ----------------
__global__ __launch_bounds__(256) void k_xw(const int* __restrict__ X,
                                            const float* __restrict__ emb,
                                            const float* __restrict__ b_ih,
                                            const float* __restrict__ b_hh,
                                            char* __restrict__ ws) {
  const bf16* wih = (const bf16*)(ws + OFF_WIH);
  bf16* xw = (bf16*)(ws + OFF_XW);
  int l = threadIdx.x & 63, wv = threadIdx.x >> 6;
  int i0 = blockIdx.x * 64 + wv * 16;
  int h0 = blockIdx.y * 64;
  const float* ap = emb + (long)X[i0 + (l & 15)] * 1024 + ((l >> 4) * 8);
  const bf16* bp = wih + (long)(h0 + (l & 15)) * 1024 + ((l >> 4) * 8);
  f32x4 zero = {0.f, 0.f, 0.f, 0.f};
  f32x4 acc[4] = {zero, zero, zero, zero};
  for (int k = 0; k < 1024; k += 32) {
    f32x4 f0 = *(const f32x4*)(ap + k);
    f32x4 f1 = *(const f32x4*)(ap + k + 4);
    bf16x8 a;
#pragma unroll
    for (int q = 0; q < 4; ++q) { a[q] = (bf16)f0[q]; a[4 + q] = (bf16)f1[q]; }
#pragma unroll
    for (int j = 0; j < 4; ++j) {
      bf16x8 b = *(const bf16x8*)(bp + j * 16 * 1024 + k);
      acc[j] = __builtin_amdgcn_mfma_f32_16x16x32_bf16(a, b, acc[j], 0, 0, 0);
    }
  }
#pragma unroll
  for (int j = 0; j < 4; ++j)
#pragma unroll
    for (int r = 0; r < 4; ++r) {
      int row = i0 + (l >> 4) * 4 + r;
      int col = h0 + j * 16 + (l & 15);
      xw[(long)row * 1024 + col] = (bf16)(acc[j][r] + b_ih[col] + b_hh[col]);
    }
}

// ---------------- group barrier: 64 blocks, flag-array + 64-lane poll ----------------
// Block j store-releases ticket to flags[j]; wave 0 polls all 64 flags (one lane each).
__device__ __forceinline__ void group_barrier(unsigned int* flags, int j, unsigned int ticket) {
  __syncthreads();                      // all block threads' writes done
  if (threadIdx.x == 0)
    __hip_atomic_store(&flags[j], ticket, __ATOMIC_RELEASE, __HIP_MEMORY_SCOPE_AGENT);
  if (threadIdx.x < 64) {
    for (;;) {
      unsigned int v = __hip_atomic_load(&flags[threadIdx.x], __ATOMIC_ACQUIRE,
                                         __HIP_MEMORY_SCOPE_AGENT);
      if (__all(v >= ticket)) break;
      __builtin_amdgcn_s_sleep(1);
    }
  }
  __syncthreads();                      // publish visibility to all waves
}

// ---------------- recurrence: 4 indep batch-groups x 64 blocks, weights in VGPRs ----------------
// group g = blockIdx&3 owns batch rows [16g,16g+16); block j = blockIdx>>2 owns h-slice
// [16j,16j+16). 4 waves K-split (256 each); per-thread (b,h) carries pre/c in registers.
__global__ __launch_bounds__(256) void k_rnn(const float* __restrict__ b_ch,
                                             const float* __restrict__ b_c2h,
                                             const float* __restrict__ c0,
                                             char* __restrict__ ws) {
  const bf16* xw = (const bf16*)(ws + OFF_XW);
  bf16* hist = (bf16*)(ws + OFF_HIST);
  bf16* cb   = (bf16*)(ws + OFF_CB);
  int g = blockIdx.x & 3, j = blockIdx.x >> 2;
  unsigned int* flags = (unsigned int*)(ws + OFF_BAR) + g * 64;

  int l = threadIdx.x & 63, wv = threadIdx.x >> 6;
  int b0 = g * 16, h0b = j * 16;
  int e = threadIdx.x;
  int eoff = (b0 + (e >> 4)) * 1024 + h0b + (e & 15);
  int gh = h0b + (e & 15);

  __shared__ float red[4][2][256];

  int lane_r = l & 15;
  int koff = wv * 256 + ((l >> 4) * 8);
  long arow = (long)(b0 + lane_r) * 1024 + koff;

  // weight fragments -> registers (96 VGPRs of bf16)
  bf16x8 whh_f[8], wch_f[8], wc2h_f[8];
  {
    const bf16* p1 = (const bf16*)(ws + OFF_WHH)  + (long)(h0b + lane_r) * 1024 + koff;
    const bf16* p2 = (const bf16*)(ws + OFF_WCH)  + (long)(h0b + lane_r) * 1024 + koff;
    const bf16* p3 = (const bf16*)(ws + OFF_WC2H) + (long)(h0b + lane_r) * 1024 + koff;
#pragma unroll
    for (int kk = 0; kk < 8; ++kk) {
      whh_f[kk]  = *(const bf16x8*)(p1 + kk * 32);
      wch_f[kk]  = *(const bf16x8*)(p2 + kk * 32);
      wc2h_f[kk] = *(const bf16x8*)(p3 + kk * 32);
    }
  }

  float bch_v = b_ch[gh], bc2h_v = b_c2h[gh];
  float c_reg = c0[eoff];
  f32x4 zero = {0.f, 0.f, 0.f, 0.f};

  for (int t = 0; t < TT; ++t) {
    const bf16* hx  = hist + (long)t * 65536;
    const bf16* cxb = cb + (long)(t & 1) * 65536;
    bf16* cyb = cb + (long)((t + 1) & 1) * 65536;

    // ---- phase A: pre = hx@Whh (+xw), cg = cx@Wch
    f32x4 ap_ = zero, ac_ = zero;
#pragma unroll
    for (int kk = 0; kk < 8; ++kk) {
      bf16x8 a1 = *(const bf16x8*)(hx + arow + kk * 32);
      ap_ = __builtin_amdgcn_mfma_f32_16x16x32_bf16(a1, whh_f[kk], ap_, 0, 0, 0);
      bf16x8 a2 = *(const bf16x8*)(cxb + arow + kk * 32);
      ac_ = __builtin_amdgcn_mfma_f32_16x16x32_bf16(a2, wch_f[kk], ac_, 0, 0, 0);
    }
#pragma unroll
    for (int r = 0; r < 4; ++r) {
      int ei = ((l >> 4) * 4 + r) * 16 + (l & 15);
      red[wv][0][ei] = ap_[r];
      red[wv][1][ei] = ac_[r];
    }
    __syncthreads();
    float pre = red[0][0][e] + red[1][0][e] + red[2][0][e] + red[3][0][e]
              + (float)xw[(long)t * 65536 + eoff];
    float cgm = red[0][1][e] + red[1][1][e] + red[2][1][e] + red[3][1][e] + bch_v;
    float gif = 1.f / (1.f + expf(-(pre + cgm)));
    float cy = gif * (c_reg + tanhf(pre));
    c_reg = cy;
    cyb[eoff] = (bf16)cy;
    group_barrier(flags, j, 2u * t + 1u);

    // ---- phase B: o = cy@Wc2h
    f32x4 ao = zero;
#pragma unroll
    for (int kk = 0; kk < 8; ++kk) {
      bf16x8 a3 = *(const bf16x8*)(cyb + arow + kk * 32);
      ao = __builtin_amdgcn_mfma_f32_16x16x32_bf16(a3, wc2h_f[kk], ao, 0, 0, 0);
    }
#pragma unroll
    for (int r = 0; r < 4; ++r)
      red[wv][0][((l >> 4) * 4 + r) * 16 + (l & 15)] = ao[r];
    __syncthreads();
    float o = red[0][0][e] + red[1][0][e] + red[2][0][e] + red[3][0][e] + bc2h_v;
    float og = 1.f / (1.f + expf(-(pre + o)));
    hist[(long)(t + 1) * 65536 + eoff] = (bf16)(og * tanhf(cy));
    group_barrier(flags, j, 2u * t + 2u);
  }
}

// ---------------- dense + softmax ----------------
__global__ __launch_bounds__(256) void k_out(const float* __restrict__ dense_b,
                                             const char* __restrict__ ws,
                                             float* __restrict__ out) {
  const bf16* h  = (const bf16*)(ws + OFF_HIST) + 65536;  // slot1.. = hy(t)
  const bf16* dw = (const bf16*)(ws + OFF_DW);
  int l = threadIdx.x & 63, wv = threadIdx.x >> 6;
  int i0 = blockIdx.x * 64 + wv * 16;
  const bf16* ap = h  + (long)(i0 + (l & 15)) * 1024 + ((l >> 4) * 8);
  const bf16* bp = dw + (long)(l & 15) * 1024 + ((l >> 4) * 8);
  f32x4 zero = {0.f, 0.f, 0.f, 0.f};
  f32x4 acc[4] = {zero, zero, zero, zero};
  for (int k = 0; k < 1024; k += 32) {
    bf16x8 a = *(const bf16x8*)(ap + k);
#pragma unroll
    for (int j = 0; j < 4; ++j) {
      bf16x8 b = *(const bf16x8*)(bp + j * 16 * 1024 + k);
      acc[j] = __builtin_amdgcn_mfma_f32_16x16x32_bf16(a, b, acc[j], 0, 0, 0);
    }
  }
  int tag0 = l & 15;
#pragma unroll
  for (int r = 0; r < 4; ++r) {
    int row = i0 + (l >> 4) * 4 + r;
    float lg[4], ex[4];
    float mx = -1e30f;
#pragma unroll
    for (int j = 0; j < 4; ++j) {
      int tag = j * 16 + tag0;
      lg[j] = (tag < NTAGS) ? (acc[j][r] + dense_b[tag]) : -1e30f;
      mx = fmaxf(mx, lg[j]);
    }
    for (int m = 1; m < 16; m <<= 1) mx = fmaxf(mx, __shfl_xor(mx, m, 64));
    float s = 0.f;
#pragma unroll
    for (int j = 0; j < 4; ++j) {
      int tag = j * 16 + tag0;
      ex[j] = (tag < NTAGS) ? expf(lg[j] - mx) : 0.f;
      s += ex[j];
    }
    for (int m = 1; m < 16; m <<= 1) s += __shfl_xor(s, m, 64);
    float inv = 1.f / s;
#pragma unroll
    for (int j = 0; j < 4; ++j) {
      int tag = j * 16 + tag0;
      if (tag < NTAGS) out[(long)row * 50 + tag] = ex[j] * inv;
    }
  }
}

extern "C" void kernel_launch(void* const* d_in, const int* in_sizes, int n_in,
                              void* d_out, int out_size, void* d_ws, size_t ws_size,
                              hipStream_t stream) {
  const int*   X        = (const int*)d_in[0];
  // d_in[1] = lengths (unused; all == T)
  const float* embedding = (const float*)d_in[2];
  const float* w_ih  = (const float*)d_in[3];
  const float* w_hh  = (const float*)d_in[4];
  const float* w_ch  = (const float*)d_in[5];
  const float* w_c2h = (const float*)d_in[6];
  const float* b_ih  = (const float*)d_in[7];
  const float* b_hh  = (const float*)d_in[8];
  const float* b_ch  = (const float*)d_in[9];
  const float* b_c2h = (const float*)d_in[10];
  const float* dense_w = (const float*)d_in[11];
  const float* dense_b = (const float*)d_in[12];
  const float* h0 = (const float*)d_in[13];
  const float* c0 = (const float*)d_in[14];
  char* ws = (char*)d_ws;
  float* out = (float*)d_out;

  k_prep<<<2048, 256, 0, stream>>>(w_ih, w_hh, w_ch, w_c2h, dense_w, h0, c0, ws);
  k_xw<<<dim3(256, 16), 256, 0, stream>>>(X, embedding, b_ih, b_hh, ws);

  void* args[] = {(void*)&b_ch, (void*)&b_c2h, (void*)&c0, (void*)&ws};
  hipLaunchCooperativeKernel((const void*)k_rnn, dim3(256), dim3(256), args, 0, stream);

  k_out<<<256, 256, 0, stream>>>(dense_b, ws, out);
}

// Round 4
// 4833.455 us; speedup vs baseline: 3.6222x; 1.2848x over previous
//
#include <hip/hip_runtime.h>
#include <hip/hip_cooperative_groups.h>

typedef __bf16 bf16;
typedef __bf16 bf16x8 __attribute__((ext_vector_type(8)));
typedef float f32x4 __attribute__((ext_vector_type(4)));

// Problem dims
#define TT 256
#define NTAGS 50

// Workspace layout (bytes)
#define OFF_WIH   0ull                       // bf16 [1024][1024]
#define OFF_WHH   (OFF_WIH  + 2097152ull)
#define OFF_WCH   (OFF_WHH  + 2097152ull)
#define OFF_WC2H  (OFF_WCH  + 2097152ull)
#define OFF_DW    (OFF_WC2H + 2097152ull)    // bf16 [64][1024] (tags padded to 64)
#define OFF_XW    (OFF_DW   + 131072ull)     // bf16 [16384][1024]  x@Wih^T + b_ih + b_hh
#define OFF_HIST  (OFF_XW   + 33554432ull)   // bf16 [257][64][1024] h history (slot0 = h0)
#define OFF_CB    (OFF_HIST + 33685504ull)   // bf16 [2][64][1024]  c state (bf16 copy)
#define OFF_BAR   (OFF_CB   + 262144ull)     // uint [4][64][32]: 1 flag per 128B line
#define N_FLAG_WORDS (4 * 64 * 32)
// total ~72.6 MB

// ---------------- prep: weights->bf16, h0/c0 state init, barrier flags=0 ----------------
__global__ void k_prep(const float* __restrict__ wih, const float* __restrict__ whh,
                       const float* __restrict__ wch, const float* __restrict__ wc2h,
                       const float* __restrict__ dw, const float* __restrict__ h0,
                       const float* __restrict__ c0, char* __restrict__ ws) {
  const long N_W = 4194304, N_DW = 65536, N_H = 65536, N_C = 65536, N_F = N_FLAG_WORDS;
  const long TOT = N_W + N_DW + N_H + N_C + N_F;
  long stride = (long)gridDim.x * blockDim.x;
  for (long idx = (long)blockIdx.x * blockDim.x + threadIdx.x; idx < TOT; idx += stride) {
    if (idx < N_W) {
      long m = idx >> 20, e = idx & 1048575;
      const float* s = (m == 0) ? wih : (m == 1) ? whh : (m == 2) ? wch : wc2h;
      ((bf16*)(ws + OFF_WIH))[idx] = (bf16)s[e];
    } else if (idx < N_W + N_DW) {
      long j = idx - N_W; long r = j >> 10, e = j & 1023;
      ((bf16*)(ws + OFF_DW))[j] = (bf16)((r < NTAGS) ? dw[r * 1024 + e] : 0.f);
    } else if (idx < N_W + N_DW + N_H) {
      long j = idx - N_W - N_DW;
      ((bf16*)(ws + OFF_HIST))[j] = (bf16)h0[j];
    } else if (idx < N_W + N_DW + N_H + N_C) {
      long j = idx - N_W - N_DW - N_H;
      ((bf16*)(ws + OFF_CB))[j] = (bf16)c0[j];
    } else {
      long j = idx - N_W - N_DW - N_H - N_C;
      ((unsigned int*)(ws + OFF_BAR))[j] = 0u;   // re-init every launch (replay safety)
    }
  }
}

// ---------------- XW = emb[X] @ Wih^T + b_ih + b_hh  (gather fused) ----------------
__global__ __launch_bounds__(256) void k_xw(const int* __restrict__ X,
                                            const float* __restrict__ emb,
                                            const float* __restrict__ b_ih,
                                            const float* __restrict__ b_hh,
                                            char* __restrict__ ws) {
  const bf16* wih = (const bf16*)(ws + OFF_WIH);
  bf16* xw = (bf16*)(ws + OFF_XW);
  int l = threadIdx.x & 63, wv = threadIdx.x >> 6;
  int i0 = blockIdx.x * 64 + wv * 16;
  int h0 = blockIdx.y * 64;
  const float* ap = emb + (long)X[i0 + (l & 15)] * 1024 + ((l >> 4) * 8);
  const bf16* bp = wih + (long)(h0 + (l & 15)) * 1024 + ((l >> 4) * 8);
  f32x4 zero = {0.f, 0.f, 0.f, 0.f};
  f32x4 acc[4] = {zero, zero, zero, zero};
  for (int k = 0; k < 1024; k += 32) {
    f32x4 f0 = *(const f32x4*)(ap + k);
    f32x4 f1 = *(const f32x4*)(ap + k + 4);
    bf16x8 a;
#pragma unroll
    for (int q = 0; q < 4; ++q) { a[q] = (bf16)f0[q]; a[4 + q] = (bf16)f1[q]; }
#pragma unroll
    for (int j = 0; j < 4; ++j) {
      bf16x8 b = *(const bf16x8*)(bp + j * 16 * 1024 + k);
      acc[j] = __builtin_amdgcn_mfma_f32_16x16x32_bf16(a, b, acc[j], 0, 0, 0);
    }
  }
#pragma unroll
  for (int j = 0; j < 4; ++j)
#pragma unroll
    for (int r = 0; r < 4; ++r) {
      int row = i0 + (l >> 4) * 4 + r;
      int col = h0 + j * 16 + (l & 15);
      xw[(long)row * 1024 + col] = (bf16)(acc[j][r] + b_ih[col] + b_hh[col]);
    }
}

// ---------------- group barrier: 64 blocks, 1 flag per cache line ----------------
// Block j store-releases ticket to flags[j*32] (its own 128B line); wave 0 polls all
// 64 lines in parallel (lane i -> flags[i*32]) with relaxed loads, then one acquire fence.
__device__ __forceinline__ void group_barrier(unsigned int* flags, int j, unsigned int ticket) {
  __syncthreads();                      // all block threads' writes issued
  if (threadIdx.x == 0)
    __hip_atomic_store(&flags[j * 32], ticket, __ATOMIC_RELEASE, __HIP_MEMORY_SCOPE_AGENT);
  if (threadIdx.x < 64) {
    const unsigned int* my = &flags[threadIdx.x * 32];
    for (;;) {
      unsigned int v = __hip_atomic_load(my, __ATOMIC_RELAXED, __HIP_MEMORY_SCOPE_AGENT);
      if (__all(v >= ticket)) break;
      __builtin_amdgcn_s_sleep(2);
    }
    __builtin_amdgcn_fence(__ATOMIC_ACQUIRE, "agent");  // invalidate L1/L2 once
  }
  __syncthreads();                      // publish visibility to all waves
}

// ---------------- recurrence: 4 indep batch-groups x 64 blocks, weights in VGPRs ----------------
// group g = blockIdx&3 owns batch rows [16g,16g+16); block j = blockIdx>>2 owns h-slice
// [16j,16j+16). 4 waves K-split (256 each); per-thread (b,h) carries pre/c in registers.
// __launch_bounds__(256,1): allow high VGPR so the 96 weight VGPRs stay resident.
__global__ __launch_bounds__(256, 1) void k_rnn(const float* __restrict__ b_ch,
                                                const float* __restrict__ b_c2h,
                                                const float* __restrict__ c0,
                                                char* __restrict__ ws) {
  const bf16* xw = (const bf16*)(ws + OFF_XW);
  bf16* hist = (bf16*)(ws + OFF_HIST);
  bf16* cb   = (bf16*)(ws + OFF_CB);
  int g = blockIdx.x & 3, j = blockIdx.x >> 2;
  unsigned int* flags = (unsigned int*)(ws + OFF_BAR) + g * 64 * 32;

  int l = threadIdx.x & 63, wv = threadIdx.x >> 6;
  int b0 = g * 16, h0b = j * 16;
  int e = threadIdx.x;
  int eoff = (b0 + (e >> 4)) * 1024 + h0b + (e & 15);
  int gh = h0b + (e & 15);

  __shared__ float red[4][2][256];

  int lane_r = l & 15;
  int koff = wv * 256 + ((l >> 4) * 8);
  long arow = (long)(b0 + lane_r) * 1024 + koff;

  // weight fragments -> registers (96 VGPRs of bf16)
  bf16x8 whh_f[8], wch_f[8], wc2h_f[8];
  {
    const bf16* p1 = (const bf16*)(ws + OFF_WHH)  + (long)(h0b + lane_r) * 1024 + koff;
    const bf16* p2 = (const bf16*)(ws + OFF_WCH)  + (long)(h0b + lane_r) * 1024 + koff;
    const bf16* p3 = (const bf16*)(ws + OFF_WC2H) + (long)(h0b + lane_r) * 1024 + koff;
#pragma unroll
    for (int kk = 0; kk < 8; ++kk) {
      whh_f[kk]  = *(const bf16x8*)(p1 + kk * 32);
      wch_f[kk]  = *(const bf16x8*)(p2 + kk * 32);
      wc2h_f[kk] = *(const bf16x8*)(p3 + kk * 32);
    }
  }

  float bch_v = b_ch[gh], bc2h_v = b_c2h[gh];
  float c_reg = c0[eoff];
  f32x4 zero = {0.f, 0.f, 0.f, 0.f};

  for (int t = 0; t < TT; ++t) {
    const bf16* hx  = hist + (long)t * 65536;
    const bf16* cxb = cb + (long)(t & 1) * 65536;
    bf16* cyb = cb + (long)((t + 1) & 1) * 65536;

    // ---- phase A: pre = hx@Whh (+xw), cg = cx@Wch
    f32x4 ap_ = zero, ac_ = zero;
#pragma unroll
    for (int kk = 0; kk < 8; ++kk) {
      bf16x8 a1 = *(const bf16x8*)(hx + arow + kk * 32);
      ap_ = __builtin_amdgcn_mfma_f32_16x16x32_bf16(a1, whh_f[kk], ap_, 0, 0, 0);
      bf16x8 a2 = *(const bf16x8*)(cxb + arow + kk * 32);
      ac_ = __builtin_amdgcn_mfma_f32_16x16x32_bf16(a2, wch_f[kk], ac_, 0, 0, 0);
    }
#pragma unroll
    for (int r = 0; r < 4; ++r) {
      int ei = ((l >> 4) * 4 + r) * 16 + (l & 15);
      red[wv][0][ei] = ap_[r];
      red[wv][1][ei] = ac_[r];
    }
    __syncthreads();
    float pre = red[0][0][e] + red[1][0][e] + red[2][0][e] + red[3][0][e]
              + (float)xw[(long)t * 65536 + eoff];
    float cgm = red[0][1][e] + red[1][1][e] + red[2][1][e] + red[3][1][e] + bch_v;
    float gif = 1.f / (1.f + expf(-(pre + cgm)));
    float cy = gif * (c_reg + tanhf(pre));
    c_reg = cy;
    cyb[eoff] = (bf16)cy;
    group_barrier(flags, j, 2u * t + 1u);

    // ---- phase B: o = cy@Wc2h
    f32x4 ao = zero;
#pragma unroll
    for (int kk = 0; kk < 8; ++kk) {
      bf16x8 a3 = *(const bf16x8*)(cyb + arow + kk * 32);
      ao = __builtin_amdgcn_mfma_f32_16x16x32_bf16(a3, wc2h_f[kk], ao, 0, 0, 0);
    }
#pragma unroll
    for (int r = 0; r < 4; ++r)
      red[wv][0][((l >> 4) * 4 + r) * 16 + (l & 15)] = ao[r];
    __syncthreads();
    float o = red[0][0][e] + red[1][0][e] + red[2][0][e] + red[3][0][e] + bc2h_v;
    float og = 1.f / (1.f + expf(-(pre + o)));
    hist[(long)(t + 1) * 65536 + eoff] = (bf16)(og * tanhf(cy));
    if (t < TT - 1) group_barrier(flags, j, 2u * t + 2u);
  }
}

// ---------------- dense + softmax ----------------
__global__ __launch_bounds__(256) void k_out(const float* __restrict__ dense_b,
                                             const char* __restrict__ ws,
                                             float* __restrict__ out) {
  const bf16* h  = (const bf16*)(ws + OFF_HIST) + 65536;  // slot1.. = hy(t)
  const bf16* dw = (const bf16*)(ws + OFF_DW);
  int l = threadIdx.x & 63, wv = threadIdx.x >> 6;
  int i0 = blockIdx.x * 64 + wv * 16;
  const bf16* ap = h  + (long)(i0 + (l & 15)) * 1024 + ((l >> 4) * 8);
  const bf16* bp = dw + (long)(l & 15) * 1024 + ((l >> 4) * 8);
  f32x4 zero = {0.f, 0.f, 0.f, 0.f};
  f32x4 acc[4] = {zero, zero, zero, zero};
  for (int k = 0; k < 1024; k += 32) {
    bf16x8 a = *(const bf16x8*)(ap + k);
#pragma unroll
    for (int j = 0; j < 4; ++j) {
      bf16x8 b = *(const bf16x8*)(bp + j * 16 * 1024 + k);
      acc[j] = __builtin_amdgcn_mfma_f32_16x16x32_bf16(a, b, acc[j], 0, 0, 0);
    }
  }
  int tag0 = l & 15;
#pragma unroll
  for (int r = 0; r < 4; ++r) {
    int row = i0 + (l >> 4) * 4 + r;
    float lg[4], ex[4];
    float mx = -1e30f;
#pragma unroll
    for (int j = 0; j < 4; ++j) {
      int tag = j * 16 + tag0;
      lg[j] = (tag < NTAGS) ? (acc[j][r] + dense_b[tag]) : -1e30f;
      mx = fmaxf(mx, lg[j]);
    }
    for (int m = 1; m < 16; m <<= 1) mx = fmaxf(mx, __shfl_xor(mx, m, 64));
    float s = 0.f;
#pragma unroll
    for (int j = 0; j < 4; ++j) {
      int tag = j * 16 + tag0;
      ex[j] = (tag < NTAGS) ? expf(lg[j] - mx) : 0.f;
      s += ex[j];
    }
    for (int m = 1; m < 16; m <<= 1) s += __shfl_xor(s, m, 64);
    float inv = 1.f / s;
#pragma unroll
    for (int j = 0; j < 4; ++j) {
      int tag = j * 16 + tag0;
      if (tag < NTAGS) out[(long)row * 50 + tag] = ex[j] * inv;
    }
  }
}

extern "C" void kernel_launch(void* const* d_in, const int* in_sizes, int n_in,
                              void* d_out, int out_size, void* d_ws, size_t ws_size,
                              hipStream_t stream) {
  const int*   X        = (const int*)d_in[0];
  // d_in[1] = lengths (unused; all == T)
  const float* embedding = (const float*)d_in[2];
  const float* w_ih  = (const float*)d_in[3];
  const float* w_hh  = (const float*)d_in[4];
  const float* w_ch  = (const float*)d_in[5];
  const float* w_c2h = (const float*)d_in[6];
  const float* b_ih  = (const float*)d_in[7];
  const float* b_hh  = (const float*)d_in[8];
  const float* b_ch  = (const float*)d_in[9];
  const float* b_c2h = (const float*)d_in[10];
  const float* dense_w = (const float*)d_in[11];
  const float* dense_b = (const float*)d_in[12];
  const float* h0 = (const float*)d_in[13];
  const float* c0 = (const float*)d_in[14];
  char* ws = (char*)d_ws;
  float* out = (float*)d_out;

  k_prep<<<2048, 256, 0, stream>>>(w_ih, w_hh, w_ch, w_c2h, dense_w, h0, c0, ws);
  k_xw<<<dim3(256, 16), 256, 0, stream>>>(X, embedding, b_ih, b_hh, ws);

  void* args[] = {(void*)&b_ch, (void*)&b_c2h, (void*)&c0, (void*)&ws};
  hipLaunchCooperativeKernel((const void*)k_rnn, dim3(256), dim3(256), args, 0, stream);

  k_out<<<256, 256, 0, stream>>>(dense_b, ws, out);
}

// Round 5
// 2862.912 us; speedup vs baseline: 6.1154x; 1.6883x over previous
//
#include <hip/hip_runtime.h>
#include <hip/hip_cooperative_groups.h>

typedef __bf16 bf16;
typedef __bf16 bf16x8 __attribute__((ext_vector_type(8)));
typedef float f32x4 __attribute__((ext_vector_type(4)));
typedef unsigned long long u64;
typedef unsigned int u32x4 __attribute__((ext_vector_type(4)));

// Problem dims
#define TT 256
#define NTAGS 50

// Workspace layout (bytes)
#define OFF_WIH   0ull                       // bf16 [1024][1024]
#define OFF_WHH   (OFF_WIH  + 2097152ull)
#define OFF_WCH   (OFF_WHH  + 2097152ull)
#define OFF_WC2H  (OFF_WCH  + 2097152ull)
#define OFF_DW    (OFF_WC2H + 2097152ull)    // bf16 [64][1024] (tags padded to 64)
#define OFF_XW    (OFF_DW   + 131072ull)     // bf16 [16384][1024]  x@Wih^T + b_ih + b_hh
#define OFF_HIST  (OFF_XW   + 33554432ull)   // bf16 [257][64][1024] h history (slot0 = h0)
#define OFF_CB    (OFF_HIST + 33685504ull)   // bf16 [2][64][1024]  c state (bf16 copy)
#define OFF_BAR   (OFF_CB   + 262144ull)     // uint [4][64][32]: 1 flag per 128B line
#define N_FLAG_WORDS (4 * 64 * 32)
// total ~72.6 MB

// Coherent (L3-meeting-point) 8B accessors: bypass the non-coherent per-XCD L2
// on both sides, so NO cache-wide release/acquire fences are needed anywhere.
__device__ __forceinline__ u64 cohload(const u64* p) {
  return __hip_atomic_load(p, __ATOMIC_RELAXED, __HIP_MEMORY_SCOPE_AGENT);
}
__device__ __forceinline__ void cohstore(u64* p, u64 v) {
  __hip_atomic_store(p, v, __ATOMIC_RELAXED, __HIP_MEMORY_SCOPE_AGENT);
}
__device__ __forceinline__ bf16x8 cohload_v8(const bf16* p) {
  union { u64 q[2]; bf16x8 v; } u;
  const u64* q = (const u64*)p;
  u.q[0] = cohload(q);
  u.q[1] = cohload(q + 1);
  return u.v;
}

// ---------------- prep: weights->bf16, h0/c0 state init, barrier flags=0 ----------------
__global__ void k_prep(const float* __restrict__ wih, const float* __restrict__ whh,
                       const float* __restrict__ wch, const float* __restrict__ wc2h,
                       const float* __restrict__ dw, const float* __restrict__ h0,
                       const float* __restrict__ c0, char* __restrict__ ws) {
  const long N_W = 4194304, N_DW = 65536, N_H = 65536, N_C = 65536, N_F = N_FLAG_WORDS;
  const long TOT = N_W + N_DW + N_H + N_C + N_F;
  long stride = (long)gridDim.x * blockDim.x;
  for (long idx = (long)blockIdx.x * blockDim.x + threadIdx.x; idx < TOT; idx += stride) {
    if (idx < N_W) {
      long m = idx >> 20, e = idx & 1048575;
      const float* s = (m == 0) ? wih : (m == 1) ? whh : (m == 2) ? wch : wc2h;
      ((bf16*)(ws + OFF_WIH))[idx] = (bf16)s[e];
    } else if (idx < N_W + N_DW) {
      long j = idx - N_W; long r = j >> 10, e = j & 1023;
      ((bf16*)(ws + OFF_DW))[j] = (bf16)((r < NTAGS) ? dw[r * 1024 + e] : 0.f);
    } else if (idx < N_W + N_DW + N_H) {
      long j = idx - N_W - N_DW;
      ((bf16*)(ws + OFF_HIST))[j] = (bf16)h0[j];
    } else if (idx < N_W + N_DW + N_H + N_C) {
      long j = idx - N_W - N_DW - N_H;
      ((bf16*)(ws + OFF_CB))[j] = (bf16)c0[j];
    } else {
      long j = idx - N_W - N_DW - N_H - N_C;
      ((unsigned int*)(ws + OFF_BAR))[j] = 0u;   // re-init every launch (replay safety)
    }
  }
}

// ---------------- XW = emb[X] @ Wih^T + b_ih + b_hh  (gather fused) ----------------
__global__ __launch_bounds__(256) void k_xw(const int* __restrict__ X,
                                            const float* __restrict__ emb,
                                            const float* __restrict__ b_ih,
                                            const float* __restrict__ b_hh,
                                            char* __restrict__ ws) {
  const bf16* wih = (const bf16*)(ws + OFF_WIH);
  bf16* xw = (bf16*)(ws + OFF_XW);
  int l = threadIdx.x & 63, wv = threadIdx.x >> 6;
  int i0 = blockIdx.x * 64 + wv * 16;
  int h0 = blockIdx.y * 64;
  const float* ap = emb + (long)X[i0 + (l & 15)] * 1024 + ((l >> 4) * 8);
  const bf16* bp = wih + (long)(h0 + (l & 15)) * 1024 + ((l >> 4) * 8);
  f32x4 zero = {0.f, 0.f, 0.f, 0.f};
  f32x4 acc[4] = {zero, zero, zero, zero};
  for (int k = 0; k < 1024; k += 32) {
    f32x4 f0 = *(const f32x4*)(ap + k);
    f32x4 f1 = *(const f32x4*)(ap + k + 4);
    bf16x8 a;
#pragma unroll
    for (int q = 0; q < 4; ++q) { a[q] = (bf16)f0[q]; a[4 + q] = (bf16)f1[q]; }
#pragma unroll
    for (int j = 0; j < 4; ++j) {
      bf16x8 b = *(const bf16x8*)(bp + j * 16 * 1024 + k);
      acc[j] = __builtin_amdgcn_mfma_f32_16x16x32_bf16(a, b, acc[j], 0, 0, 0);
    }
  }
#pragma unroll
  for (int j = 0; j < 4; ++j)
#pragma unroll
    for (int r = 0; r < 4; ++r) {
      int row = i0 + (l >> 4) * 4 + r;
      int col = h0 + j * 16 + (l & 15);
      xw[(long)row * 1024 + col] = (bf16)(acc[j][r] + b_ih[col] + b_hh[col]);
    }
}

// ---------------- recurrence: 4 indep batch-groups x 64 blocks ----------------
// group g = blockIdx&3 owns batch rows [16g,16g+16); block j = blockIdx>>2 owns h-slice
// [16j,16j+16). 4 waves K-split (256 each); per-thread (b,h) carries pre/c in registers.
// All cross-block data (cy, hist) moves via agent-scope relaxed atomics (L3 meeting
// point) => barrier is just vmcnt(0) + relaxed flag store + relaxed poll. No fences.
__global__ __launch_bounds__(256, 1) void k_rnn(const float* __restrict__ b_ch,
                                                const float* __restrict__ b_c2h,
                                                const float* __restrict__ c0,
                                                char* __restrict__ ws) {
  const bf16* xw = (const bf16*)(ws + OFF_XW);
  bf16* hist = (bf16*)(ws + OFF_HIST);
  bf16* cb   = (bf16*)(ws + OFF_CB);
  int g = blockIdx.x & 3, j = blockIdx.x >> 2;
  unsigned int* flags = (unsigned int*)(ws + OFF_BAR) + g * 64 * 32;

  int l = threadIdx.x & 63, wv = threadIdx.x >> 6;
  int b0 = g * 16, h0b = j * 16;
  int e = threadIdx.x;
  int eoff = (b0 + (e >> 4)) * 1024 + h0b + (e & 15);
  int gh = h0b + (e & 15);

  __shared__ float red[4][2][256];
  __shared__ bf16 xfer[256];   // 16x16 outgoing tile staging

  int lane_r = l & 15;
  int koff = wv * 256 + ((l >> 4) * 8);
  long arow = (long)(b0 + lane_r) * 1024 + koff;

  // weight fragments -> registers, pinned with opaque asm so the compiler
  // cannot rematerialize the loads inside the t-loop (r4: VGPR=68 showed it did).
  u32x4 whh_r[8], wch_r[8], wc2h_r[8];
  {
    const bf16* p1 = (const bf16*)(ws + OFF_WHH)  + (long)(h0b + lane_r) * 1024 + koff;
    const bf16* p2 = (const bf16*)(ws + OFF_WCH)  + (long)(h0b + lane_r) * 1024 + koff;
    const bf16* p3 = (const bf16*)(ws + OFF_WC2H) + (long)(h0b + lane_r) * 1024 + koff;
#pragma unroll
    for (int kk = 0; kk < 8; ++kk) {
      whh_r[kk]  = *(const u32x4*)(p1 + kk * 32);
      wch_r[kk]  = *(const u32x4*)(p2 + kk * 32);
      wc2h_r[kk] = *(const u32x4*)(p3 + kk * 32);
      asm volatile("" : "+v"(whh_r[kk]), "+v"(wch_r[kk]), "+v"(wc2h_r[kk]));
    }
  }

  float bch_v = b_ch[gh], bc2h_v = b_c2h[gh];
  float c_reg = c0[eoff];
  f32x4 zero = {0.f, 0.f, 0.f, 0.f};

  int srow = e >> 2, spart = e & 3;  // tile-store mapping for threads 0..63

  for (int t = 0; t < TT; ++t) {
    const bf16* hx  = hist + (long)t * 65536;
    const bf16* cxb = cb + (long)(t & 1) * 65536;
    bf16* cyb = cb + (long)((t + 1) & 1) * 65536;

    // ---- phase A: pre = hx@Whh (+xw), cg = cx@Wch
    f32x4 ap_ = zero, ac_ = zero;
#pragma unroll
    for (int kk = 0; kk < 8; ++kk) {
      bf16x8 a1 = cohload_v8(hx + arow + kk * 32);
      ap_ = __builtin_amdgcn_mfma_f32_16x16x32_bf16(
          a1, __builtin_bit_cast(bf16x8, whh_r[kk]), ap_, 0, 0, 0);
      bf16x8 a2 = cohload_v8(cxb + arow + kk * 32);
      ac_ = __builtin_amdgcn_mfma_f32_16x16x32_bf16(
          a2, __builtin_bit_cast(bf16x8, wch_r[kk]), ac_, 0, 0, 0);
    }
#pragma unroll
    for (int r = 0; r < 4; ++r) {
      int ei = ((l >> 4) * 4 + r) * 16 + (l & 15);
      red[wv][0][ei] = ap_[r];
      red[wv][1][ei] = ac_[r];
    }
    __syncthreads();
    float pre = red[0][0][e] + red[1][0][e] + red[2][0][e] + red[3][0][e]
              + (float)xw[(long)t * 65536 + eoff];
    float cgm = red[0][1][e] + red[1][1][e] + red[2][1][e] + red[3][1][e] + bch_v;
    float gif = 1.f / (1.f + expf(-(pre + cgm)));
    float cy = gif * (c_reg + tanhf(pre));
    c_reg = cy;
    xfer[e] = (bf16)cy;
    __syncthreads();                    // xfer ready; red reads done
    if (e < 64)
      cohstore((u64*)(cyb + (long)(b0 + srow) * 1024 + h0b) + spart, ((u64*)xfer)[e]);
    asm volatile("s_waitcnt vmcnt(0)" ::: "memory");   // wave0's tile stores ack'd @L3
    unsigned int tkA = 2u * t + 1u;
    if (e == 0)
      __hip_atomic_store(&flags[j * 32], tkA, __ATOMIC_RELAXED, __HIP_MEMORY_SCOPE_AGENT);
    if (e < 64) {
      const unsigned int* my = &flags[e * 32];
      while (!__all(__hip_atomic_load(my, __ATOMIC_RELAXED, __HIP_MEMORY_SCOPE_AGENT) >= tkA))
        __builtin_amdgcn_s_sleep(1);
    }
    asm volatile("" ::: "memory");
    __syncthreads();

    // ---- phase B: o = cy@Wc2h
    f32x4 ao = zero;
#pragma unroll
    for (int kk = 0; kk < 8; ++kk) {
      bf16x8 a3 = cohload_v8(cyb + arow + kk * 32);
      ao = __builtin_amdgcn_mfma_f32_16x16x32_bf16(
          a3, __builtin_bit_cast(bf16x8, wc2h_r[kk]), ao, 0, 0, 0);
    }
#pragma unroll
    for (int r = 0; r < 4; ++r)
      red[wv][0][((l >> 4) * 4 + r) * 16 + (l & 15)] = ao[r];
    __syncthreads();
    float o = red[0][0][e] + red[1][0][e] + red[2][0][e] + red[3][0][e] + bc2h_v;
    float og = 1.f / (1.f + expf(-(pre + o)));
    float hy = og * tanhf(cy);
    xfer[e] = (bf16)hy;
    __syncthreads();
    if (e < 64)
      cohstore((u64*)(hist + (long)(t + 1) * 65536 + (long)(b0 + srow) * 1024 + h0b) + spart,
               ((u64*)xfer)[e]);
    if (t < TT - 1) {
      asm volatile("s_waitcnt vmcnt(0)" ::: "memory");
      unsigned int tkB = 2u * t + 2u;
      if (e == 0)
        __hip_atomic_store(&flags[j * 32], tkB, __ATOMIC_RELAXED, __HIP_MEMORY_SCOPE_AGENT);
      if (e < 64) {
        const unsigned int* my = &flags[e * 32];
        while (!__all(__hip_atomic_load(my, __ATOMIC_RELAXED, __HIP_MEMORY_SCOPE_AGENT) >= tkB))
          __builtin_amdgcn_s_sleep(1);
      }
      asm volatile("" ::: "memory");
      __syncthreads();
    }
  }
}

// ---------------- dense + softmax ----------------
__global__ __launch_bounds__(256) void k_out(const float* __restrict__ dense_b,
                                             const char* __restrict__ ws,
                                             float* __restrict__ out) {
  const bf16* h  = (const bf16*)(ws + OFF_HIST) + 65536;  // slot1.. = hy(t)
  const bf16* dw = (const bf16*)(ws + OFF_DW);
  int l = threadIdx.x & 63, wv = threadIdx.x >> 6;
  int i0 = blockIdx.x * 64 + wv * 16;
  const bf16* ap = h  + (long)(i0 + (l & 15)) * 1024 + ((l >> 4) * 8);
  const bf16* bp = dw + (long)(l & 15) * 1024 + ((l >> 4) * 8);
  f32x4 zero = {0.f, 0.f, 0.f, 0.f};
  f32x4 acc[4] = {zero, zero, zero, zero};
  for (int k = 0; k < 1024; k += 32) {
    bf16x8 a = *(const bf16x8*)(ap + k);
#pragma unroll
    for (int j = 0; j < 4; ++j) {
      bf16x8 b = *(const bf16x8*)(bp + j * 16 * 1024 + k);
      acc[j] = __builtin_amdgcn_mfma_f32_16x16x32_bf16(a, b, acc[j], 0, 0, 0);
    }
  }
  int tag0 = l & 15;
#pragma unroll
  for (int r = 0; r < 4; ++r) {
    int row = i0 + (l >> 4) * 4 + r;
    float lg[4], ex[4];
    float mx = -1e30f;
#pragma unroll
    for (int j = 0; j < 4; ++j) {
      int tag = j * 16 + tag0;
      lg[j] = (tag < NTAGS) ? (acc[j][r] + dense_b[tag]) : -1e30f;
      mx = fmaxf(mx, lg[j]);
    }
    for (int m = 1; m < 16; m <<= 1) mx = fmaxf(mx, __shfl_xor(mx, m, 64));
    float s = 0.f;
#pragma unroll
    for (int j = 0; j < 4; ++j) {
      int tag = j * 16 + tag0;
      ex[j] = (tag < NTAGS) ? expf(lg[j] - mx) : 0.f;
      s += ex[j];
    }
    for (int m = 1; m < 16; m <<= 1) s += __shfl_xor(s, m, 64);
    float inv = 1.f / s;
#pragma unroll
    for (int j = 0; j < 4; ++j) {
      int tag = j * 16 + tag0;
      if (tag < NTAGS) out[(long)row * 50 + tag] = ex[j] * inv;
    }
  }
}

extern "C" void kernel_launch(void* const* d_in, const int* in_sizes, int n_in,
                              void* d_out, int out_size, void* d_ws, size_t ws_size,
                              hipStream_t stream) {
  const int*   X        = (const int*)d_in[0];
  // d_in[1] = lengths (unused; all == T)
  const float* embedding = (const float*)d_in[2];
  const float* w_ih  = (const float*)d_in[3];
  const float* w_hh  = (const float*)d_in[4];
  const float* w_ch  = (const float*)d_in[5];
  const float* w_c2h = (const float*)d_in[6];
  const float* b_ih  = (const float*)d_in[7];
  const float* b_hh  = (const float*)d_in[8];
  const float* b_ch  = (const float*)d_in[9];
  const float* b_c2h = (const float*)d_in[10];
  const float* dense_w = (const float*)d_in[11];
  const float* dense_b = (const float*)d_in[12];
  const float* h0 = (const float*)d_in[13];
  const float* c0 = (const float*)d_in[14];
  char* ws = (char*)d_ws;
  float* out = (float*)d_out;

  k_prep<<<2048, 256, 0, stream>>>(w_ih, w_hh, w_ch, w_c2h, dense_w, h0, c0, ws);
  k_xw<<<dim3(256, 16), 256, 0, stream>>>(X, embedding, b_ih, b_hh, ws);

  void* args[] = {(void*)&b_ch, (void*)&b_c2h, (void*)&c0, (void*)&ws};
  hipLaunchCooperativeKernel((const void*)k_rnn, dim3(256), dim3(256), args, 0, stream);

  k_out<<<256, 256, 0, stream>>>(dense_b, ws, out);
}